// Round 1
// baseline (1660.029 us; speedup 1.0000x reference)
//
#include <hip/hip_runtime.h>
#include <math.h>

// Problem constants (fixed by setup_inputs)
#define BB 32
#define CC 64
#define HH 112
#define WW 112

constexpr int TILE = 16;   // 16x16 output pixels per block
constexpr int OCB  = 32;   // output channels per block
constexpr int ICB  = 16;   // input-channel chunk staged in LDS
constexpr float EPSV = 1e-5f;

// 0=relu, 1=identity, 2=tanh, 3=sigmoid
__device__ __forceinline__ float apply_act(float v, int code) {
    if (code == 0) return v > 0.f ? v : 0.f;
    if (code == 1) return v;
    if (code == 2) return tanhf(v);
    return 1.f / (1.f + __expf(-v));
}

// FIRST: out = act_feat(BN1(conv1(in)))            (writes h to ws)
// !FIRST: out = BN2(conv2(in)) + act_sc(x0)        (writes final out)
template<bool FIRST>
__global__ __launch_bounds__(256)
void conv_bn_act(const float* __restrict__ in,
                 const float* __restrict__ wgt,     // [64][64][3][3] OIHW
                 const float* __restrict__ gamma, const float* __restrict__ beta,
                 const float* __restrict__ mean,  const float* __restrict__ var,
                 const int*   __restrict__ codes,   // [C*H*W]
                 const float* __restrict__ x0,      // original x (only !FIRST)
                 float* __restrict__ out)
{
    __shared__ float sIn[ICB][18 * 20];       // 18 rows x 18 cols, stride 20
    __shared__ float sW[OCB * ICB * 9];

    const int t    = threadIdx.x;
    const int bx   = blockIdx.x;              // 49 tiles * 2 oc-groups
    const int n    = blockIdx.y;
    const int ocg  = bx & 1;
    const int tile = bx >> 1;
    const int ty0  = (tile / 7) * TILE;
    const int tx0  = (tile % 7) * TILE;

    const int lane = t & 63;
    const int wv   = t >> 6;                  // wave id 0..3 -> oc octet
    const int qy   = lane >> 3, qx = lane & 7;
    const int py0  = ty0 + qy * 2, px0 = tx0 + qx * 2;
    const int ocb  = ocg * OCB;

    float acc[4][8];
    #pragma unroll
    for (int p = 0; p < 4; ++p)
        #pragma unroll
        for (int j = 0; j < 8; ++j) acc[p][j] = 0.f;

    for (int icc = 0; icc < CC; icc += ICB) {
        // ---- stage input tile (ICB x 18 x 18, zero-padded halo) ----
        for (int idx = t; idx < ICB * 18 * 18; idx += 256) {
            int ic  = idx / 324, rem = idx % 324;
            int ry  = rem / 18,  rx  = rem % 18;
            int gy  = ty0 + ry - 1, gx = tx0 + rx - 1;
            float v = 0.f;
            if ((unsigned)gy < (unsigned)HH && (unsigned)gx < (unsigned)WW)
                v = in[(((size_t)n * CC + (icc + ic)) * HH + gy) * WW + gx];
            sIn[ic][ry * 20 + rx] = v;
        }
        // ---- stage weights (OCB x ICB x 9) ----
        for (int idx = t; idx < OCB * ICB * 9; idx += 256) {
            int oc = idx / (ICB * 9), rem = idx % (ICB * 9);
            int ic = rem / 9,         k   = rem % 9;
            sW[idx] = wgt[(((size_t)(ocb + oc)) * CC + (icc + ic)) * 9 + k];
        }
        __syncthreads();

        // ---- compute ----
        for (int ic = 0; ic < ICB; ++ic) {
            float r[4][4];
            #pragma unroll
            for (int a = 0; a < 4; ++a)
                #pragma unroll
                for (int b = 0; b < 4; ++b)
                    r[a][b] = sIn[ic][(qy * 2 + a) * 20 + qx * 2 + b];

            #pragma unroll
            for (int j = 0; j < 8; ++j) {
                const float* wp = &sW[((wv * 8 + j) * ICB + ic) * 9];
                float w0 = wp[0], w1 = wp[1], w2 = wp[2];
                float w3 = wp[3], w4 = wp[4], w5 = wp[5];
                float w6 = wp[6], w7 = wp[7], w8 = wp[8];
                #pragma unroll
                for (int p = 0; p < 4; ++p) {
                    const int dy = p >> 1, dx = p & 1;
                    float s = acc[p][j];
                    s += r[dy + 0][dx + 0] * w0 + r[dy + 0][dx + 1] * w1 + r[dy + 0][dx + 2] * w2;
                    s += r[dy + 1][dx + 0] * w3 + r[dy + 1][dx + 1] * w4 + r[dy + 1][dx + 2] * w5;
                    s += r[dy + 2][dx + 0] * w6 + r[dy + 2][dx + 1] * w7 + r[dy + 2][dx + 2] * w8;
                    acc[p][j] = s;
                }
            }
        }
        __syncthreads();
    }

    // ---- epilogue: BN + activation (+ shortcut) ----
    #pragma unroll
    for (int j = 0; j < 8; ++j) {
        const int oc = ocb + wv * 8 + j;
        const float sc = gamma[oc] / sqrtf(var[oc] + EPSV);
        const float sh = beta[oc] - mean[oc] * sc;
        #pragma unroll
        for (int p = 0; p < 4; ++p) {
            const int py = py0 + (p >> 1), px = px0 + (p & 1);
            const size_t oidx = (((size_t)n * CC + oc) * HH + py) * WW + px;
            const int code = codes[(oc * HH + py) * WW + px];
            float v = acc[p][j] * sc + sh;
            if (FIRST) {
                out[oidx] = apply_act(v, code);
            } else {
                out[oidx] = v + apply_act(x0[oidx], code);
            }
        }
    }
}

extern "C" void kernel_launch(void* const* d_in, const int* in_sizes, int n_in,
                              void* d_out, int out_size, void* d_ws, size_t ws_size,
                              hipStream_t stream) {
    const float* x        = (const float*)d_in[0];
    const float* conv1_w  = (const float*)d_in[1];
    const float* conv2_w  = (const float*)d_in[2];
    const float* gamma1   = (const float*)d_in[3];
    const float* beta1    = (const float*)d_in[4];
    const float* mean1    = (const float*)d_in[5];
    const float* var1     = (const float*)d_in[6];
    const float* gamma2   = (const float*)d_in[7];
    const float* beta2    = (const float*)d_in[8];
    const float* mean2    = (const float*)d_in[9];
    const float* var2     = (const float*)d_in[10];
    const int*   codes_f  = (const int*)d_in[11];
    const int*   codes_sc = (const int*)d_in[12];
    float* out = (float*)d_out;
    float* h   = (float*)d_ws;   // [32][64][112][112] fp32 = 102.8 MB

    dim3 grid(49 * 2, BB, 1);
    dim3 block(256, 1, 1);

    conv_bn_act<true><<<grid, block, 0, stream>>>(
        x, conv1_w, gamma1, beta1, mean1, var1, codes_f, nullptr, h);
    conv_bn_act<false><<<grid, block, 0, stream>>>(
        h, conv2_w, gamma2, beta2, mean2, var2, codes_sc, x, out);
}

// Round 2
// 763.252 us; speedup vs baseline: 2.1749x; 2.1749x over previous
//
#include <hip/hip_runtime.h>
#include <math.h>

#define BB 32
#define CC 64
#define HH 112
#define WW 112

typedef __bf16  bf16x8 __attribute__((ext_vector_type(8)));
typedef float   f32x4  __attribute__((ext_vector_type(4)));
typedef int     int4v  __attribute__((ext_vector_type(4)));
typedef unsigned short ushort4v __attribute__((ext_vector_type(4)));

constexpr float EPSV = 1e-5f;

__device__ __forceinline__ unsigned short bf16bits(float f) {
    __bf16 b = (__bf16)f;
    return __builtin_bit_cast(unsigned short, b);
}

// 0=relu, 1=identity, 2=tanh, 3=sigmoid
__device__ __forceinline__ float apply_act(float v, int code) {
    float r = v > 0.f ? v : 0.f;
    if (code == 1) r = v;
    else if (code == 2) r = tanhf(v);
    else if (code == 3) r = 1.f / (1.f + __expf(-v));
    return r;
}

// ---------------------------------------------------------------------------
// Pre-pack conv weights (fp32 OIHW) into bf16 A-fragment order:
//   [conv 2][ocg 2][step 36][lane 64][j 8]   step = (tap*2+icch)*2+mt
//   lane l -> oc = ocg*32 + mt*16 + (l&15),  ic = icch*32 + (l>>4)*8 + j
// ---------------------------------------------------------------------------
__global__ __launch_bounds__(256)
void prepack_w(const float* __restrict__ w1, const float* __restrict__ w2,
               unsigned short* __restrict__ wpk)
{
    int idx  = blockIdx.x * 256 + threadIdx.x;     // < 73728
    int cg   = idx / 18432;                        // conv*2 + ocg
    int rem  = idx % 18432;
    int step = rem >> 9;
    int e    = rem & 511;
    int l    = e >> 3;
    int j    = e & 7;
    int conv = cg >> 1, ocg = cg & 1;
    int mt   = step & 1;
    int icch = (step >> 1) & 1;
    int tap  = step >> 2;
    int oc   = ocg * 32 + mt * 16 + (l & 15);
    int ic   = icch * 32 + (l >> 4) * 8 + j;
    const float* w = conv ? w2 : w1;
    wpk[idx] = bf16bits(w[(oc * 64 + ic) * 9 + tap]);
}

// ---------------------------------------------------------------------------
// Fused conv3x3 + BN (+act / +shortcut) via mfma_f32_16x16x32_bf16.
// FIRST:  in = x fp32 NCHW,  out = h bf16 NHWC (act_feat applied)
// !FIRST: in = h bf16 NHWC,  out = fp32 NCHW (+ act_sc(x) shortcut)
// Block: 256 thr / 4 waves; 32 oc x 16x16 px. Wave: 32 oc x 4 rows x 16 cols.
// ---------------------------------------------------------------------------
template<bool FIRST>
__global__ __launch_bounds__(256, 2)
void conv_mfma(const float* __restrict__ xin,            // FIRST input
               const unsigned short* __restrict__ hin,   // !FIRST input
               const unsigned short* __restrict__ wpk,   // this conv's packed W
               const float* __restrict__ gamma, const float* __restrict__ beta,
               const float* __restrict__ mean,  const float* __restrict__ var,
               const int*   __restrict__ codes,
               const float* __restrict__ x0,             // !FIRST shortcut src
               unsigned short* __restrict__ hout,        // FIRST output
               float* __restrict__ out)                  // !FIRST output
{
    __shared__ char smem[57600] __attribute__((aligned(16)));
    // sIn: bytes [0, 20736)  layout ((icblk*324 + pxlin)*8 + ic&7) bf16
    // sW : bytes [20736, 57600) layout (step*64 + lane)*8 bf16

    const int t    = threadIdx.x;
    const int lane = t & 63;
    const int wv   = t >> 6;
    const int l15  = lane & 15;
    const int l4   = lane >> 4;
    const int bx   = blockIdx.x;          // 0..97
    const int n    = blockIdx.y;
    const int ocg  = bx & 1;
    const int tile = bx >> 1;
    const int ty0  = (tile / 7) * 16;
    const int tx0  = (tile % 7) * 16;

    // ---- stage packed weights: 2304 x 16B, coalesced, conflict-free ----
    {
        const int4v* gw = (const int4v*)(wpk + ocg * 18432);
        int4v* lw = (int4v*)(smem + 20736);
        #pragma unroll
        for (int k = 0; k < 9; ++k) lw[t + k * 256] = gw[t + k * 256];
    }

    f32x4 acc[2][4];
    #pragma unroll
    for (int m = 0; m < 2; ++m)
        #pragma unroll
        for (int r = 0; r < 4; ++r) acc[m][r] = (f32x4){0.f, 0.f, 0.f, 0.f};

    // per-lane invariant base addresses (bytes)
    const int inbase = l15 * 16 + l4 * 5184 + wv * 1152;
    const int wbase  = 20736 + lane * 16;

    #pragma unroll
    for (int icch = 0; icch < 2; ++icch) {
        // ---------------- stage input chunk: 32 ic x 18 x 18 ----------------
        if (FIRST) {
            #pragma unroll
            for (int k = 0; k < 41; ++k) {
                int idx = t + k * 256;
                if (idx < 10368) {
                    int icl = idx / 324, pxl = idx % 324;
                    int ry = pxl / 18, rx = pxl % 18;
                    int gy = ty0 + ry - 1, gx = tx0 + rx - 1;
                    float v = 0.f;
                    if ((unsigned)gy < (unsigned)HH && (unsigned)gx < (unsigned)WW)
                        v = xin[(((size_t)n * CC + icch * 32 + icl) * HH + gy) * WW + gx];
                    ((unsigned short*)smem)[((icl >> 3) * 324 + pxl) * 8 + (icl & 7)] = bf16bits(v);
                }
            }
        } else {
            #pragma unroll
            for (int k = 0; k < 6; ++k) {
                int idx = t + k * 256;          // 1296 16B-chunks
                if (idx < 1296) {
                    int icb = idx / 324, pxl = idx % 324;
                    int ry = pxl / 18, rx = pxl % 18;
                    int gy = ty0 + ry - 1, gx = tx0 + rx - 1;
                    int4v v = (int4v){0, 0, 0, 0};
                    if ((unsigned)gy < (unsigned)HH && (unsigned)gx < (unsigned)WW)
                        v = *(const int4v*)(hin + (((size_t)n * HH + gy) * WW + gx) * 64
                                                + icch * 32 + icb * 8);
                    *(int4v*)(smem + idx * 16) = v;
                }
            }
        }
        __syncthreads();

        // ---------------- 9 taps x K=32: 6 ds_read_b128 + 8 MFMA per tap ----
        #pragma unroll
        for (int ky = 0; ky < 3; ++ky) {
            #pragma unroll
            for (int kx = 0; kx < 3; ++kx) {
                const int tap = ky * 3 + kx;
                bf16x8 a0 = *(const bf16x8*)(smem + wbase + ((tap * 2 + icch) * 2 + 0) * 1024);
                bf16x8 a1 = *(const bf16x8*)(smem + wbase + ((tap * 2 + icch) * 2 + 1) * 1024);
                #pragma unroll
                for (int r = 0; r < 4; ++r) {
                    bf16x8 b = *(const bf16x8*)(smem + inbase + (((r + ky) * 18) + kx) * 16);
                    acc[0][r] = __builtin_amdgcn_mfma_f32_16x16x32_bf16(a0, b, acc[0][r], 0, 0, 0);
                    acc[1][r] = __builtin_amdgcn_mfma_f32_16x16x32_bf16(a1, b, acc[1][r], 0, 0, 0);
                }
            }
        }
        __syncthreads();
    }

    // ---------------- epilogue: BN + act (+shortcut) ----------------
    #pragma unroll
    for (int mt = 0; mt < 2; ++mt) {
        const int ocb = ocg * 32 + mt * 16 + l4 * 4;
        float sc[4], sh[4];
        #pragma unroll
        for (int reg = 0; reg < 4; ++reg) {
            const int oc = ocb + reg;
            sc[reg] = gamma[oc] * rsqrtf(var[oc] + EPSV);
            sh[reg] = beta[oc] - mean[oc] * sc[reg];
        }
        #pragma unroll
        for (int r = 0; r < 4; ++r) {
            const int py = ty0 + wv * 4 + r;
            const int px = tx0 + l15;
            if (FIRST) {
                ushort4v pack;
                #pragma unroll
                for (int reg = 0; reg < 4; ++reg) {
                    float v = acc[mt][r][reg] * sc[reg] + sh[reg];
                    const int code = codes[((ocb + reg) * HH + py) * WW + px];
                    pack[reg] = bf16bits(apply_act(v, code));
                }
                *(ushort4v*)(hout + (((size_t)n * HH + py) * WW + px) * 64 + ocb) = pack;
            } else {
                #pragma unroll
                for (int reg = 0; reg < 4; ++reg) {
                    const int oc = ocb + reg;
                    float v = acc[mt][r][reg] * sc[reg] + sh[reg];
                    const size_t oidx = (((size_t)n * CC + oc) * HH + py) * WW + px;
                    const int code = codes[(oc * HH + py) * WW + px];
                    out[oidx] = v + apply_act(x0[oidx], code);
                }
            }
        }
    }
}

extern "C" void kernel_launch(void* const* d_in, const int* in_sizes, int n_in,
                              void* d_out, int out_size, void* d_ws, size_t ws_size,
                              hipStream_t stream) {
    const float* x        = (const float*)d_in[0];
    const float* conv1_w  = (const float*)d_in[1];
    const float* conv2_w  = (const float*)d_in[2];
    const float* gamma1   = (const float*)d_in[3];
    const float* beta1    = (const float*)d_in[4];
    const float* mean1    = (const float*)d_in[5];
    const float* var1     = (const float*)d_in[6];
    const float* gamma2   = (const float*)d_in[7];
    const float* beta2    = (const float*)d_in[8];
    const float* mean2    = (const float*)d_in[9];
    const float* var2     = (const float*)d_in[10];
    const int*   codes_f  = (const int*)d_in[11];
    const int*   codes_sc = (const int*)d_in[12];
    float* out = (float*)d_out;

    // ws layout: h bf16 NHWC [32][112][112][64] = 51,380,224 B ; packed W after
    unsigned short* h   = (unsigned short*)d_ws;
    unsigned short* wpk = (unsigned short*)((char*)d_ws + 51380224);

    prepack_w<<<288, 256, 0, stream>>>(conv1_w, conv2_w, wpk);

    dim3 grid(98, BB);
    conv_mfma<true><<<grid, 256, 0, stream>>>(
        x, nullptr, wpk, gamma1, beta1, mean1, var1,
        codes_f, nullptr, h, nullptr);
    conv_mfma<false><<<grid, 256, 0, stream>>>(
        nullptr, h, wpk + 36864, gamma2, beta2, mean2, var2,
        codes_sc, x, nullptr, out);
}

// Round 5
// 493.125 us; speedup vs baseline: 3.3663x; 1.5478x over previous
//
#include <hip/hip_runtime.h>
#include <math.h>

#define BB 32
#define CC 64
#define HH 112
#define WW 112
#define HW 12544   // 112*112

typedef __bf16  bf16x8 __attribute__((ext_vector_type(8)));
typedef float   f32x4  __attribute__((ext_vector_type(4)));
typedef int     int4v  __attribute__((ext_vector_type(4)));
typedef unsigned short ushort4v __attribute__((ext_vector_type(4)));

constexpr float EPSV = 1e-5f;

__device__ __forceinline__ unsigned short bf16bits(float f) {
    __bf16 b = (__bf16)f;
    return __builtin_bit_cast(unsigned short, b);
}

// 0=relu 1=identity 2=tanh 3=sigmoid — branchless (divergence-free)
__device__ __forceinline__ float apply_act(float v, int code) {
    float e2 = __expf(2.f * v);
    float th = 1.f - 2.f / (e2 + 1.f);
    float sg = 1.f / (1.f + __expf(-v));
    float r = fmaxf(v, 0.f);
    r = (code == 1) ? v  : r;
    r = (code == 2) ? th : r;
    r = (code == 3) ? sg : r;
    return r;
}

// ---------------------------------------------------------------------------
// Pack conv weights to bf16 A-frag order. Per conv: 72 steps x 512 elements.
// step = (icch*9+tap)*4+mt ; byte addr = step*1024 + lane*16
// lane l, elem j: oc = mt*16+(l&15), ic = icch*32+(l>>4)*8+j
// ---------------------------------------------------------------------------
__global__ __launch_bounds__(256)
void prepack_w(const float* __restrict__ w1, const float* __restrict__ w2,
               unsigned short* __restrict__ wpk)
{
    int idx  = blockIdx.x * 256 + threadIdx.x;   // < 73728 = 2 convs * 36864
    int conv = idx / 36864;
    int r    = idx % 36864;
    int step = r >> 9;            // 0..71
    int e    = r & 511;
    int l    = e >> 3;
    int j    = e & 7;
    int mt   = step & 3;
    int ti   = step >> 2;         // icch*9 + tap, 0..17
    int tap  = ti % 9;
    int icch = ti / 9;            // 0..1
    int oc   = mt * 16 + (l & 15);
    int ic   = icch * 32 + (l >> 4) * 8 + j;
    const float* w = conv ? w2 : w1;
    wpk[idx] = bf16bits(w[(oc * 64 + ic) * 9 + tap]);
}

// ---------------------------------------------------------------------------
// x fp32 NCHW -> bf16 NHWC for a 16-image group. Block: 64 px x 64 ic.
// ---------------------------------------------------------------------------
__global__ __launch_bounds__(256)
void x_to_nhwc(const float* __restrict__ x, unsigned short* __restrict__ xo, int n0)
{
    int t   = threadIdx.x;
    int px  = blockIdx.x * 64 + (t >> 2);
    int nl  = blockIdx.y;                 // local image 0..15
    int icq = t & 3;
    const float* src = x + ((size_t)(n0 + nl) * CC + icq * 16) * HW + px;
    ushort4v p[4];
    #pragma unroll
    for (int q = 0; q < 4; ++q)
        #pragma unroll
        for (int j = 0; j < 4; ++j)
            p[q][j] = bf16bits(src[(q * 4 + j) * HW]);
    unsigned short* dst = xo + ((size_t)nl * HW + px) * CC + icq * 16;
    *(int4v*)(dst)     = ((int4v*)p)[0];
    *(int4v*)(dst + 8) = ((int4v*)p)[1];
}

// codes_feat NCHW int -> NHWC int (no batch dim)
__global__ __launch_bounds__(256)
void codes_to_nhwc(const int* __restrict__ ci, int* __restrict__ co)
{
    int t   = threadIdx.x;
    int px  = blockIdx.x * 64 + (t >> 2);
    int icq = t & 3;
    const int* src = ci + icq * 16 * HW + px;
    int4v p[4];
    #pragma unroll
    for (int q = 0; q < 4; ++q)
        #pragma unroll
        for (int j = 0; j < 4; ++j)
            p[q][j] = src[(q * 4 + j) * HW];
    int* dst = co + (size_t)px * CC + icq * 16;
    #pragma unroll
    for (int q = 0; q < 4; ++q) *(int4v*)(dst + q * 4) = p[q];
}

// ---------------------------------------------------------------------------
// conv3x3 (64->64) + BN (+act / +shortcut), mfma_f32_16x16x32_bf16.
// Block: 256 thr / 4 waves, 64 oc x 16x16 px tile. Wave: 64 oc x 4 rows x 16 cols.
// Input bf16 NHWC; LDS: 2 x (324 px x 4 slots x 16B) XOR-swizzled;
// A-frags streamed from global wpk (L2-resident).
// FIRST: input = xbf (local images), writes h bf16 NHWC at image n+nof.
// !FIRST: input = h (global), writes out fp32 NCHW + shortcut.
// ---------------------------------------------------------------------------
template<bool FIRST>
__global__ __launch_bounds__(256, 3)
void conv_mfma(const unsigned short* __restrict__ in_nhwc,
               const unsigned short* __restrict__ wpk,    // this conv's 72-step pack
               const float* __restrict__ gamma, const float* __restrict__ beta,
               const float* __restrict__ mean,  const float* __restrict__ var,
               const int*   __restrict__ codes_t,   // FIRST: NHWC codes
               const int*   __restrict__ codes_sc,  // !FIRST: NCHW codes
               const float* __restrict__ x0,        // !FIRST shortcut src (fp32 NCHW)
               unsigned short* __restrict__ hout,   // FIRST out (bf16 NHWC)
               float* __restrict__ out,             // !FIRST out (fp32 NCHW)
               int nof)
{
    __shared__ char smem[41472];   // 2 buffers x 1296 chunks x 16B
    const int t    = threadIdx.x;
    const int lane = t & 63, wv = t >> 6;
    const int l15  = lane & 15, l4 = lane >> 4;
    const int tile = blockIdx.x, n = blockIdx.y;
    const int ty0  = (tile / 7) * 16, tx0 = (tile % 7) * 16;

    // ---- staging addresses: 16B chunks, chunk c = px*4 + slot (1296 total) ----
    int gofs[6]; bool inb[6];
    #pragma unroll
    for (int i = 0; i < 6; ++i) {
        int c = t + i * 256;
        int px = c >> 2, slot = c & 3;
        int ry = px / 18, rx = px % 18;
        int gy = ty0 + ry - 1, gx = tx0 + rx - 1;
        inb[i] = (c < 1296) && ((unsigned)gy < (unsigned)HH) && ((unsigned)gx < (unsigned)WW);
        int slotp = slot ^ ((px >> 1) & 3);          // content swizzle (write side)
        gofs[i] = (((n * HH + gy) * WW + gx) * CC + slotp * 8) * 2;   // bytes
    }

    // ---- B-read address table (read-side swizzle matches write side) ----
    int baddr[6][3];
    #pragma unroll
    for (int row = 0; row < 6; ++row)
        #pragma unroll
        for (int kx = 0; kx < 3; ++kx) {
            int px = (wv * 4 + row) * 18 + l15 + kx;
            baddr[row][kx] = px * 64 + ((l4 ^ ((px >> 1) & 3)) << 4);
        }

    const char* wb = (const char*)wpk + lane * 16;

    // ---- stage ic-chunk 0 -> buf0 (zeros in halo) ----
    #pragma unroll
    for (int i = 0; i < 6; ++i) {
        if (i < 5 || t < 16) {                        // c < 1296 only
            int4v v = {0, 0, 0, 0};
            if (inb[i]) v = *(const int4v*)((const char*)in_nhwc + gofs[i]);
            *(int4v*)(smem + (t + i * 256) * 16) = v;
        }
    }
    __syncthreads();

    // ---- T14: issue ic-chunk 1 loads now, LDS-write after step 8 ----
    int4v hold[6];
    #pragma unroll
    for (int i = 0; i < 6; ++i) {
        int4v v = {0, 0, 0, 0};
        if (inb[i]) v = *(const int4v*)((const char*)in_nhwc + gofs[i] + 64);
        hold[i] = v;
    }

    f32x4 acc[4][4];
    #pragma unroll
    for (int mt = 0; mt < 4; ++mt)
        #pragma unroll
        for (int r = 0; r < 4; ++r) acc[mt][r] = (f32x4){0.f, 0.f, 0.f, 0.f};

    // ---- main loop: 18 steps (2 ic-chunks x 9 taps) ----
    #pragma unroll
    for (int s = 0; s < 18; ++s) {
        const int icch = s / 9, tap = s % 9, ky = tap / 3, kx = tap % 3;
        bf16x8 a[4];
        #pragma unroll
        for (int mt = 0; mt < 4; ++mt)
            a[mt] = *(const bf16x8*)(wb + (s * 4 + mt) * 1024);
        bf16x8 b[4];
        #pragma unroll
        for (int r = 0; r < 4; ++r)
            b[r] = *(const bf16x8*)(smem + baddr[r + ky][kx] + icch * 20736);
        #pragma unroll
        for (int r = 0; r < 4; ++r)
            #pragma unroll
            for (int mt = 0; mt < 4; ++mt)
                acc[mt][r] = __builtin_amdgcn_mfma_f32_16x16x32_bf16(a[mt], b[r], acc[mt][r], 0, 0, 0);
        if (s == 8) {
            #pragma unroll
            for (int i = 0; i < 6; ++i)
                if (i < 5 || t < 16)                  // c < 1296 only (no OOB!)
                    *(int4v*)(smem + 20736 + (t + i * 256) * 16) = hold[i];
            __syncthreads();
        }
    }

    // ---- epilogue: BN + act (+shortcut) ----
    float sc[4][4], sh[4][4];
    #pragma unroll
    for (int mt = 0; mt < 4; ++mt)
        #pragma unroll
        for (int g = 0; g < 4; ++g) {
            int oc = mt * 16 + l4 * 4 + g;
            float s0 = gamma[oc] * rsqrtf(var[oc] + EPSV);
            sc[mt][g] = s0;
            sh[mt][g] = beta[oc] - mean[oc] * s0;
        }

    if (FIRST) {
        #pragma unroll
        for (int r = 0; r < 4; ++r) {
            int py = ty0 + wv * 4 + r, px = tx0 + l15;
            size_t pbase = ((size_t)(n + nof) * HW + py * WW + px) * CC;
            const int* ct = codes_t + (py * WW + px) * CC;
            #pragma unroll
            for (int mt = 0; mt < 4; ++mt) {
                int4v cd = *(const int4v*)(ct + mt * 16 + l4 * 4);
                ushort4v pk;
                #pragma unroll
                for (int g = 0; g < 4; ++g) {
                    float v = acc[mt][r][g] * sc[mt][g] + sh[mt][g];
                    pk[g] = bf16bits(apply_act(v, cd[g]));
                }
                *(ushort4v*)(hout + pbase + mt * 16 + l4 * 4) = pk;
            }
        }
    } else {
        #pragma unroll
        for (int r = 0; r < 4; ++r) {
            int py = ty0 + wv * 4 + r, px = tx0 + l15;
            #pragma unroll
            for (int mt = 0; mt < 4; ++mt) {
                #pragma unroll
                for (int g = 0; g < 4; ++g) {
                    int oc = mt * 16 + l4 * 4 + g;
                    size_t oidx = ((size_t)n * CC + oc) * HW + py * WW + px;
                    int code = codes_sc[oc * HW + py * WW + px];
                    float v = acc[mt][r][g] * sc[mt][g] + sh[mt][g];
                    out[oidx] = v + apply_act(x0[oidx], code);
                }
            }
        }
    }
}

extern "C" void kernel_launch(void* const* d_in, const int* in_sizes, int n_in,
                              void* d_out, int out_size, void* d_ws, size_t ws_size,
                              hipStream_t stream) {
    const float* x        = (const float*)d_in[0];
    const float* conv1_w  = (const float*)d_in[1];
    const float* conv2_w  = (const float*)d_in[2];
    const float* gamma1   = (const float*)d_in[3];
    const float* beta1    = (const float*)d_in[4];
    const float* mean1    = (const float*)d_in[5];
    const float* var1     = (const float*)d_in[6];
    const float* gamma2   = (const float*)d_in[7];
    const float* beta2    = (const float*)d_in[8];
    const float* mean2    = (const float*)d_in[9];
    const float* var2     = (const float*)d_in[10];
    const int*   codes_f  = (const int*)d_in[11];
    const int*   codes_sc = (const int*)d_in[12];
    float* out = (float*)d_out;

    // ws layout (80.43 MB total; round-1 proved ws_size >= 102.76 MB):
    //   h bf16 NHWC (32 img)   [        0,  51380224)
    //   xbf bf16 NHWC (16 img) [ 51380224,  77070336)
    //   codes_t NHWC int       [ 77070336,  80281600)
    //   wpk (2 convs)          [ 80281600,  80429056)
    unsigned short* h    = (unsigned short*)d_ws;
    unsigned short* xbf  = (unsigned short*)((char*)d_ws + 51380224);
    int*            ctns = (int*)((char*)d_ws + 77070336);
    unsigned short* wpk  = (unsigned short*)((char*)d_ws + 80281600);

    prepack_w<<<288, 256, 0, stream>>>(conv1_w, conv2_w, wpk);
    codes_to_nhwc<<<196, 256, 0, stream>>>(codes_f, ctns);

    // conv1 in two 16-image groups (xbf buffer reused)
    for (int g = 0; g < 2; ++g) {
        int n0 = g * 16;
        x_to_nhwc<<<dim3(196, 16), 256, 0, stream>>>(x, xbf, n0);
        conv_mfma<true><<<dim3(49, 16), 256, 0, stream>>>(
            xbf, wpk, gamma1, beta1, mean1, var1, ctns, nullptr, nullptr,
            h, nullptr, n0);
    }
    conv_mfma<false><<<dim3(49, BB), 256, 0, stream>>>(
        h, wpk + 36864, gamma2, beta2, mean2, var2, nullptr, codes_sc, x,
        nullptr, out, 0);
}

// Round 6
// 471.959 us; speedup vs baseline: 3.5173x; 1.0448x over previous
//
#include <hip/hip_runtime.h>
#include <math.h>

#define BB 32
#define CC 64
#define HH 112
#define WW 112
#define HW 12544   // 112*112

typedef __bf16  bf16x8 __attribute__((ext_vector_type(8)));
typedef float   f32x4  __attribute__((ext_vector_type(4)));
typedef int     int4v  __attribute__((ext_vector_type(4)));
typedef unsigned short ushort4v __attribute__((ext_vector_type(4)));

constexpr float EPSV = 1e-5f;

__device__ __forceinline__ unsigned short bf16bits(float f) {
    __bf16 b = (__bf16)f;
    return __builtin_bit_cast(unsigned short, b);
}

// 0=relu 1=identity 2=tanh 3=sigmoid — branchless (divergence-free)
__device__ __forceinline__ float apply_act(float v, int code) {
    float e2 = __expf(2.f * v);
    float th = 1.f - 2.f / (e2 + 1.f);
    float sg = 1.f / (1.f + __expf(-v));
    float r = fmaxf(v, 0.f);
    r = (code == 1) ? v  : r;
    r = (code == 2) ? th : r;
    r = (code == 3) ? sg : r;
    return r;
}

// ---------------------------------------------------------------------------
// Pack conv weights to bf16 A-frag order. Per conv: 72 steps x 512 elements.
// step = (icch*9+tap)*4+mt ; byte addr = step*1024 + lane*16
// lane l, elem j: oc = mt*16+(l&15), ic = icch*32+(l>>4)*8+j
// ---------------------------------------------------------------------------
__global__ __launch_bounds__(256)
void prepack_w(const float* __restrict__ w1, const float* __restrict__ w2,
               unsigned short* __restrict__ wpk)
{
    int idx  = blockIdx.x * 256 + threadIdx.x;   // < 73728 = 2 convs * 36864
    int conv = idx / 36864;
    int r    = idx % 36864;
    int step = r >> 9;            // 0..71
    int e    = r & 511;
    int l    = e >> 3;
    int j    = e & 7;
    int mt   = step & 3;
    int ti   = step >> 2;         // icch*9 + tap, 0..17
    int tap  = ti % 9;
    int icch = ti / 9;            // 0..1
    int oc   = mt * 16 + (l & 15);
    int ic   = icch * 32 + (l >> 4) * 8 + j;
    const float* w = conv ? w2 : w1;
    wpk[idx] = bf16bits(w[(oc * 64 + ic) * 9 + tap]);
}

// ---------------------------------------------------------------------------
// x fp32 NCHW -> bf16 NHWC for a 16-image group. Block: 64 px x 64 ic.
// ---------------------------------------------------------------------------
__global__ __launch_bounds__(256)
void x_to_nhwc(const float* __restrict__ x, unsigned short* __restrict__ xo, int n0)
{
    int t   = threadIdx.x;
    int px  = blockIdx.x * 64 + (t >> 2);
    int nl  = blockIdx.y;                 // local image 0..15
    int icq = t & 3;
    const float* src = x + ((size_t)(n0 + nl) * CC + icq * 16) * HW + px;
    ushort4v p[4];
    #pragma unroll
    for (int q = 0; q < 4; ++q)
        #pragma unroll
        for (int j = 0; j < 4; ++j)
            p[q][j] = bf16bits(src[(q * 4 + j) * HW]);
    unsigned short* dst = xo + ((size_t)nl * HW + px) * CC + icq * 16;
    *(int4v*)(dst)     = ((int4v*)p)[0];
    *(int4v*)(dst + 8) = ((int4v*)p)[1];
}

// codes_feat NCHW int -> NHWC byte table (802816 B, L2-resident)
__global__ __launch_bounds__(256)
void codes_to_bytes_nhwc(const int* __restrict__ ci, unsigned char* __restrict__ co)
{
    int idx  = blockIdx.x * 256 + threadIdx.x;   // < 200704 = 12544 px * 16 quads
    int px   = idx / 16;
    int quad = idx % 16;
    unsigned char b[4];
    #pragma unroll
    for (int j = 0; j < 4; ++j)
        b[j] = (unsigned char)ci[(quad * 4 + j) * HW + px];
    *(unsigned int*)(co + (size_t)px * CC + quad * 4) = *(unsigned int*)b;
}

// codes_sc NCHW int -> NCHW byte table
__global__ __launch_bounds__(256)
void codes_to_bytes_nchw(const int* __restrict__ ci, unsigned char* __restrict__ co)
{
    int idx = blockIdx.x * 256 + threadIdx.x;    // < 200704 (4 codes each)
    int4v v = *(const int4v*)(ci + idx * 4);
    unsigned char b[4];
    #pragma unroll
    for (int j = 0; j < 4; ++j) b[j] = (unsigned char)v[j];
    *(unsigned int*)(co + idx * 4) = *(unsigned int*)b;
}

// ---------------------------------------------------------------------------
// conv3x3 (64->64) + BN (+act / +shortcut), mfma_f32_16x16x32_bf16.
// Block: 256 thr / 4 waves, 64 oc x 16x16 px tile.
// XCD strip-swizzle: all 7 x-tiles of one (ty,n) row-band share dispatch-idx%8
// -> same XCD L2 -> x-neighbor half-line reads/writes merge to full lines.
// Input bf16 NHWC; LDS: 2 x (324 px x 4 slots x 16B) XOR-swizzled;
// A-frags double-buffered from global wpk (L2-resident).
// ---------------------------------------------------------------------------
template<bool FIRST>
__global__ __launch_bounds__(256, 3)
void conv_mfma(const unsigned short* __restrict__ in_nhwc,
               const unsigned short* __restrict__ wpk,    // this conv's 72-step pack
               const float* __restrict__ gamma, const float* __restrict__ beta,
               const float* __restrict__ mean,  const float* __restrict__ var,
               const unsigned char* __restrict__ cbt,   // FIRST: NHWC byte codes
               const unsigned char* __restrict__ cbs,   // !FIRST: NCHW byte codes
               const float* __restrict__ x0,        // !FIRST shortcut src (fp32 NCHW)
               unsigned short* __restrict__ hout,   // FIRST out (bf16 NHWC)
               float* __restrict__ out,             // !FIRST out (fp32 NCHW)
               int nof)
{
    __shared__ char smem[41472];   // 2 buffers x 1296 chunks x 16B
    const int t    = threadIdx.x;
    const int lane = t & 63, wv = t >> 6;
    const int l15  = lane & 15, l4 = lane >> 4;

    // ---- strip swizzle: bid -> (xcd, strip, j); strip = ty + 7*n ----------
    const int bid   = blockIdx.x;
    const int xcd   = bid & 7;
    const int q     = bid >> 3;
    const int strip = xcd + 8 * (q / 7);
    const int j7    = q % 7;              // x-tile within strip
    const int ty    = strip % 7;
    const int n     = strip / 7;          // local image index
    const int ty0   = ty * 16, tx0 = j7 * 16;

    // ---- staging addresses: 16B chunks, chunk c = px*4 + slot (1296 total) ----
    int gofs[6]; bool inb[6];
    #pragma unroll
    for (int i = 0; i < 6; ++i) {
        int c = t + i * 256;
        int px = c >> 2, slot = c & 3;
        int ry = px / 18, rx = px % 18;
        int gy = ty0 + ry - 1, gx = tx0 + rx - 1;
        inb[i] = (c < 1296) && ((unsigned)gy < (unsigned)HH) && ((unsigned)gx < (unsigned)WW);
        int slotp = slot ^ ((px >> 1) & 3);          // content swizzle (write side)
        gofs[i] = (((n * HH + gy) * WW + gx) * CC + slotp * 8) * 2;   // bytes
    }

    // ---- B-read address table (read-side swizzle matches write side) ----
    int baddr[6][3];
    #pragma unroll
    for (int row = 0; row < 6; ++row)
        #pragma unroll
        for (int kx = 0; kx < 3; ++kx) {
            int px = (wv * 4 + row) * 18 + l15 + kx;
            baddr[row][kx] = px * 64 + ((l4 ^ ((px >> 1) & 3)) << 4);
        }

    const char* wb = (const char*)wpk + lane * 16;

    // ---- stage ic-chunk 0 -> buf0 (zeros in halo) ----
    #pragma unroll
    for (int i = 0; i < 6; ++i) {
        if (i < 5 || t < 16) {                        // c < 1296 only
            int4v v = {0, 0, 0, 0};
            if (inb[i]) v = *(const int4v*)((const char*)in_nhwc + gofs[i]);
            *(int4v*)(smem + (t + i * 256) * 16) = v;
        }
    }
    // A-frags for step 0 (overlaps with staging latency)
    bf16x8 a_cur[4], a_nxt[4];
    #pragma unroll
    for (int mt = 0; mt < 4; ++mt) a_cur[mt] = *(const bf16x8*)(wb + mt * 1024);
    __syncthreads();

    // ---- T14: issue ic-chunk 1 loads now, LDS-write after step 8 ----
    int4v hold[6];
    #pragma unroll
    for (int i = 0; i < 6; ++i) {
        int4v v = {0, 0, 0, 0};
        if (inb[i]) v = *(const int4v*)((const char*)in_nhwc + gofs[i] + 64);
        hold[i] = v;
    }

    f32x4 acc[4][4];
    #pragma unroll
    for (int mt = 0; mt < 4; ++mt)
        #pragma unroll
        for (int r = 0; r < 4; ++r) acc[mt][r] = (f32x4){0.f, 0.f, 0.f, 0.f};

    // ---- main loop: 18 steps (2 ic-chunks x 9 taps), A double-buffered ----
    #pragma unroll
    for (int s = 0; s < 18; ++s) {
        const int icch = s / 9, tap = s % 9, ky = tap / 3, kx = tap % 3;
        if (s < 17) {
            #pragma unroll
            for (int mt = 0; mt < 4; ++mt)
                a_nxt[mt] = *(const bf16x8*)(wb + ((s + 1) * 4 + mt) * 1024);
        }
        bf16x8 b[4];
        #pragma unroll
        for (int r = 0; r < 4; ++r)
            b[r] = *(const bf16x8*)(smem + baddr[r + ky][kx] + icch * 20736);
        #pragma unroll
        for (int r = 0; r < 4; ++r)
            #pragma unroll
            for (int mt = 0; mt < 4; ++mt)
                acc[mt][r] = __builtin_amdgcn_mfma_f32_16x16x32_bf16(a_cur[mt], b[r], acc[mt][r], 0, 0, 0);
        if (s == 8) {
            #pragma unroll
            for (int i = 0; i < 6; ++i)
                if (i < 5 || t < 16)                  // c < 1296 only
                    *(int4v*)(smem + 20736 + (t + i * 256) * 16) = hold[i];
            __syncthreads();
        }
        #pragma unroll
        for (int mt = 0; mt < 4; ++mt) a_cur[mt] = a_nxt[mt];
    }

    // ---- epilogue: BN + act (+shortcut) ----
    float sc[4][4], sh[4][4];
    #pragma unroll
    for (int mt = 0; mt < 4; ++mt)
        #pragma unroll
        for (int g = 0; g < 4; ++g) {
            int oc = mt * 16 + l4 * 4 + g;
            float s0 = gamma[oc] * rsqrtf(var[oc] + EPSV);
            sc[mt][g] = s0;
            sh[mt][g] = beta[oc] - mean[oc] * s0;
        }

    if (FIRST) {
        #pragma unroll
        for (int r = 0; r < 4; ++r) {
            int py = ty0 + wv * 4 + r, px = tx0 + l15;
            size_t pbase = ((size_t)(n + nof) * HW + py * WW + px) * CC;
            const unsigned char* ct = cbt + ((size_t)py * WW + px) * CC;
            #pragma unroll
            for (int mt = 0; mt < 4; ++mt) {
                unsigned int cd4 = *(const unsigned int*)(ct + mt * 16 + l4 * 4);
                ushort4v pk;
                #pragma unroll
                for (int g = 0; g < 4; ++g) {
                    float v = acc[mt][r][g] * sc[mt][g] + sh[mt][g];
                    pk[g] = bf16bits(apply_act(v, (int)((cd4 >> (8 * g)) & 255u)));
                }
                *(ushort4v*)(hout + pbase + mt * 16 + l4 * 4) = pk;
            }
        }
    } else {
        #pragma unroll
        for (int r = 0; r < 4; ++r) {
            int py = ty0 + wv * 4 + r, px = tx0 + l15;
            #pragma unroll
            for (int mt = 0; mt < 4; ++mt) {
                #pragma unroll
                for (int g = 0; g < 4; ++g) {
                    int oc = mt * 16 + l4 * 4 + g;
                    size_t oidx = ((size_t)n * CC + oc) * HW + py * WW + px;
                    int code = (int)cbs[oc * HW + py * WW + px];
                    float v = acc[mt][r][g] * sc[mt][g] + sh[mt][g];
                    out[oidx] = v + apply_act(x0[oidx], code);
                }
            }
        }
    }
}

extern "C" void kernel_launch(void* const* d_in, const int* in_sizes, int n_in,
                              void* d_out, int out_size, void* d_ws, size_t ws_size,
                              hipStream_t stream) {
    const float* x        = (const float*)d_in[0];
    const float* conv1_w  = (const float*)d_in[1];
    const float* conv2_w  = (const float*)d_in[2];
    const float* gamma1   = (const float*)d_in[3];
    const float* beta1    = (const float*)d_in[4];
    const float* mean1    = (const float*)d_in[5];
    const float* var1     = (const float*)d_in[6];
    const float* gamma2   = (const float*)d_in[7];
    const float* beta2    = (const float*)d_in[8];
    const float* mean2    = (const float*)d_in[9];
    const float* var2     = (const float*)d_in[10];
    const int*   codes_f  = (const int*)d_in[11];
    const int*   codes_sc = (const int*)d_in[12];
    float* out = (float*)d_out;

    // ws layout (78.9 MB; proven ws_size >= 102.76 MB):
    //   h bf16 NHWC (32 img)   [        0,  51380224)
    //   xbf bf16 NHWC (16 img) [ 51380224,  77070336)
    //   wpk (2 convs)          [ 77070336,  77217792)
    //   cbt NHWC bytes         [ 77217792,  78020608)
    //   cbs NCHW bytes         [ 78020608,  78823424)
    unsigned short* h    = (unsigned short*)d_ws;
    unsigned short* xbf  = (unsigned short*)((char*)d_ws + 51380224);
    unsigned short* wpk  = (unsigned short*)((char*)d_ws + 77070336);
    unsigned char*  cbt  = (unsigned char*)((char*)d_ws + 77217792);
    unsigned char*  cbs  = (unsigned char*)((char*)d_ws + 78020608);

    prepack_w<<<288, 256, 0, stream>>>(conv1_w, conv2_w, wpk);
    codes_to_bytes_nhwc<<<784, 256, 0, stream>>>(codes_f, cbt);
    codes_to_bytes_nchw<<<784, 256, 0, stream>>>(codes_sc, cbs);

    // conv1 in two 16-image groups (xbf buffer reused); 784 blocks each (%8==0)
    for (int g = 0; g < 2; ++g) {
        int n0 = g * 16;
        x_to_nhwc<<<dim3(196, 16), 256, 0, stream>>>(x, xbf, n0);
        conv_mfma<true><<<784, 256, 0, stream>>>(
            xbf, wpk, gamma1, beta1, mean1, var1, cbt, nullptr, nullptr,
            h, nullptr, n0);
    }
    // conv2: 1568 blocks (%8==0)
    conv_mfma<false><<<1568, 256, 0, stream>>>(
        h, wpk + 36864, gamma2, beta2, mean2, var2, nullptr, cbs, x,
        nullptr, out, 0);
}